// Round 11
// baseline (1213.022 us; speedup 1.0000x reference)
//
#include <hip/hip_runtime.h>
#include <cmath>

#define WIN 64
#define HID 512
#define BATCH 1024
#define KIN 518

typedef _Float16 f16;
typedef _Float16 half8 __attribute__((ext_vector_type(8)));
typedef float f32x4 __attribute__((ext_vector_type(4)));

struct Sched { int starts[63]; int ends[63]; };
struct TL { int t[8]; };

// ---------------------------------------------------------------------------
// Parallel logsig scan (validated r3-r10) + in-kernel flag table.
// Writes lsh[t][b][64] fp16.
// ---------------------------------------------------------------------------
__global__ __launch_bounds__(256)
void logsig_scan(const float* __restrict__ z, Sched sc,
                 ushort* __restrict__ lsh, float scale) {
  __shared__ float zs[3000];
  __shared__ float Cs[20][3];
  __shared__ float wtot[4][6];
  __shared__ float earr[63][6];
  __shared__ short fe_s[1000];
  const int tid = threadIdx.x;
  const int b = blockIdx.x;
  const int ln = tid & 63, wv = tid >> 6;

  const float4* zrow = (const float4*)(z + (size_t)b * 3000);
  for (int i = tid; i < 750; i += 256) ((float4*)zs)[i] = zrow[i];
  for (int i = tid; i < 1000; i += 256) fe_s[i] = -1;
  if (tid == 0) { Cs[0][0] = 0.f; Cs[0][1] = 0.f; Cs[0][2] = 0.f; }
  __syncthreads();
  if (tid < 63) fe_s[sc.ends[tid]] = (short)tid;
  __syncthreads();

  const int p0 = 4 * tid + 1;
  int myfe[4];
#pragma unroll
  for (int i = 0; i < 4; ++i) myfe[i] = (p0 + i <= 999) ? fe_s[p0 + i] : -1;

  float d0 = 0.f, d1 = 0.f, d2 = 0.f, A0 = 0.f, A1 = 0.f, A2 = 0.f;
  if (p0 <= 999) {
    float b0 = 0.f, b1 = 0.f, b2 = 0.f;
#pragma unroll
    for (int i = 0; i < 4; ++i) {
      int p = p0 + i;
      if (p > 999) break;
      float n0 = b0 + zs[p * 3 + 0] * scale;
      float n1 = b1 + zs[p * 3 + 1] * scale;
      float n2 = b2 + zs[p * 3 + 2] * scale;
      A0 += 0.5f * (b0 * n1 - b1 * n0);
      A1 += 0.5f * (b0 * n2 - b2 * n0);
      A2 += 0.5f * (b1 * n2 - b2 * n1);
      b0 = n0; b1 = n1; b2 = n2;
    }
    d0 = b0; d1 = b1; d2 = b2;
  }

#pragma unroll
  for (int off = 1; off < 64; off <<= 1) {
    float e0 = __shfl(d0, ln - off), e1 = __shfl(d1, ln - off), e2 = __shfl(d2, ln - off);
    float eA0 = __shfl(A0, ln - off), eA1 = __shfl(A1, ln - off), eA2 = __shfl(A2, ln - off);
    if (ln >= off) {
      A0 = eA0 + A0 + 0.5f * (e0 * d1 - e1 * d0);
      A1 = eA1 + A1 + 0.5f * (e0 * d2 - e2 * d0);
      A2 = eA2 + A2 + 0.5f * (e1 * d2 - e2 * d1);
      d0 += e0; d1 += e1; d2 += e2;
    }
  }
  if (ln == 63) {
    wtot[wv][0] = d0; wtot[wv][1] = d1; wtot[wv][2] = d2;
    wtot[wv][3] = A0; wtot[wv][4] = A1; wtot[wv][5] = A2;
  }
  __syncthreads();

  float P0 = 0.f, P1 = 0.f, P2 = 0.f, PA0 = 0.f, PA1 = 0.f, PA2 = 0.f;
  for (int w = 0; w < wv; ++w) {
    float t0 = wtot[w][0], t1 = wtot[w][1], t2 = wtot[w][2];
    PA0 = PA0 + wtot[w][3] + 0.5f * (P0 * t1 - P1 * t0);
    PA1 = PA1 + wtot[w][4] + 0.5f * (P0 * t2 - P2 * t0);
    PA2 = PA2 + wtot[w][5] + 0.5f * (P1 * t2 - P2 * t1);
    P0 += t0; P1 += t1; P2 += t2;
  }
  float L0 = __shfl(d0, ln - 1), L1 = __shfl(d1, ln - 1), L2 = __shfl(d2, ln - 1);
  float LA0 = __shfl(A0, ln - 1), LA1 = __shfl(A1, ln - 1), LA2 = __shfl(A2, ln - 1);
  if (ln == 0) { L0 = L1 = L2 = LA0 = LA1 = LA2 = 0.f; }
  float bp0 = P0 + L0, bp1 = P1 + L1, bp2 = P2 + L2;
  float C0 = PA0 + LA0 + 0.5f * (P0 * L1 - P1 * L0);
  float C1 = PA1 + LA1 + 0.5f * (P0 * L2 - P2 * L0);
  float C2 = PA2 + LA2 + 0.5f * (P1 * L2 - P2 * L1);

  if (p0 <= 999) {
#pragma unroll
    for (int i = 0; i < 4; ++i) {
      int p = p0 + i;
      if (p > 999) break;
      float n0 = bp0 + zs[p * 3 + 0] * scale;
      float n1 = bp1 + zs[p * 3 + 1] * scale;
      float n2 = bp2 + zs[p * 3 + 2] * scale;
      C0 += 0.5f * (bp0 * n1 - bp1 * n0);
      C1 += 0.5f * (bp0 * n2 - bp2 * n0);
      C2 += 0.5f * (bp1 * n2 - bp2 * n1);
      bp0 = n0; bp1 = n1; bp2 = n2;
      if (p % 50 == 0) {
        int s = p / 50;
        Cs[s][0] = C0; Cs[s][1] = C1; Cs[s][2] = C2;
      }
      int k = myfe[i];
      if (k >= 0) {
        earr[k][0] = bp0; earr[k][1] = bp1; earr[k][2] = bp2;
        earr[k][3] = C0;  earr[k][4] = C1;  earr[k][5] = C2;
      }
    }
  }
  __syncthreads();

  if (tid < 63) {
    int s = sc.starts[tid] / 50;
    half8 v = {};
    v[0] = (f16)earr[tid][0]; v[1] = (f16)earr[tid][1]; v[2] = (f16)earr[tid][2];
    v[3] = (f16)(earr[tid][3] - Cs[s][0]);
    v[4] = (f16)(earr[tid][4] - Cs[s][1]);
    v[5] = (f16)(earr[tid][5] - Cs[s][2]);
    half8 zz = {};
    half8* d = (half8*)(lsh + ((size_t)(tid + 1) * BATCH + b) * 64);
    d[0] = v;
#pragma unroll
    for (int q = 1; q < 8; ++q) d[q] = zz;
  } else if (tid == 63) {
    half8 zz = {};
    half8* d = (half8*)(lsh + (size_t)b * 64);
#pragma unroll
    for (int q = 0; q < 8; ++q) d[q] = zz;
  }
}

// ---------------------------------------------------------------------------
// One-shot f32 -> f16 convert of all three weight matrices (K zero-padded).
// ---------------------------------------------------------------------------
__global__ __launch_bounds__(256)
void cvt_all(const float* __restrict__ W1, const float* __restrict__ W2,
             const float* __restrict__ W3, ushort* __restrict__ W1h,
             ushort* __restrict__ W2h, ushort* __restrict__ W3h) {
  const int n1 = HID * (576 / 8);
  const int n2 = HID * (HID / 8);
  int i = blockIdx.x * 256 + threadIdx.x;
  const float* src; ushort* dst; int Ks, Kd;
  if (i < n1)           { src = W1; dst = W1h; Ks = KIN; Kd = 576; }
  else if (i < n1 + n2) { src = W2; dst = W2h; Ks = HID; Kd = HID; i -= n1; }
  else if (i < n1 + 2 * n2) { src = W3; dst = W3h; Ks = HID; Kd = HID; i -= n1 + n2; }
  else return;
  int nblk = Kd >> 3;
  int row = i / nblk, k = (i - row * nblk) * 8;
  half8 v;
#pragma unroll
  for (int j = 0; j < 8; ++j) {
    int kk = k + j;
    float f = (kk < Ks) ? src[(size_t)row * Ks + kk] : 0.f;
    v[j] = (f16)f;
  }
  *(half8*)&dst[(size_t)row * Kd + k] = v;
}

// ---------------------------------------------------------------------------
// Fused 3-layer round kernel: ONE launch per gated segment. Block = 64 batch
// rows x full 512 cols; h lives in 64KB XOR-swizzled LDS between layers
// (r5-validated layout); W streams L2 -> registers with a 2-deep statically-
// unrolled ping-pong (compiler emits counted vmcnt). 512 thr = 8 waves, each
// owning a 64-col strip (acc 4x4). Summation order identical to r8-r10
// (kt ascending, ls tail last) -> bit-identical results.
// ---------------------------------------------------------------------------
template<int FIRST>
__global__ __launch_bounds__(512, 1)
void round3(const ushort* __restrict__ carry,
            const ushort* __restrict__ lsh, TL tl,
            const ushort* __restrict__ W1h,   // [512][576]
            const ushort* __restrict__ W2h,   // [512][512]
            const ushort* __restrict__ W3h,   // [512][512]
            const float* __restrict__ b1,
            const float* __restrict__ b2,
            const float* __restrict__ b3,
            ushort* __restrict__ Hall) {
  __shared__ ushort Xs[64 * 512];             // 64KB
  char* const xb = (char*)Xs;
  const int tid = threadIdx.x;
  const int wv = tid >> 6, ln = tid & 63;
  const int l15 = ln & 15, l4 = ln >> 4;
  const int br = blockIdx.x;
  const int t = tl.t[br >> 4];
  const int rbg = (br & 15) * 64;             // batch row base
  const int nb = wv * 64;                     // wave col strip

  f32x4 acc[4][4];

  // ---- stage carry -> swizzled LDS (skipped round 0) ----
  if (!FIRST) {
    for (int i = tid; i < 4096; i += 512) {
      int r = i >> 6, gq = i & 63;
      half8 v = *(const half8*)(carry + (size_t)(rbg + r) * HID + gq * 8);
      *(half8*)(xb + (size_t)r * 1024 + ((gq ^ (r & 7)) << 4)) = v;
    }
  }
  __syncthreads();

#define LOADW(DST, WPTR, LDW, KT)                                             \
  _Pragma("unroll")                                                           \
  for (int kk = 0; kk < 2; ++kk)                                              \
    _Pragma("unroll")                                                         \
    for (int ni = 0; ni < 4; ++ni)                                            \
      DST[kk * 4 + ni] = *(const half8*)((WPTR) +                             \
          (size_t)(nb + ni * 16 + l15) * (LDW) + (KT) * 64 + kk * 32 + l4 * 8);

#define COMPUTE(WREG, KT)                                                     \
  _Pragma("unroll")                                                           \
  for (int kk = 0; kk < 2; ++kk) {                                            \
    half8 xf[4];                                                              \
    _Pragma("unroll")                                                         \
    for (int mi = 0; mi < 4; ++mi) {                                          \
      int r = mi * 16 + l15;                                                  \
      int g = (KT) * 8 + kk * 4 + l4;                                         \
      xf[mi] = *(const half8*)(xb + (size_t)r * 1024 + ((g ^ (r & 7)) << 4)); \
    }                                                                         \
    _Pragma("unroll")                                                         \
    for (int mi = 0; mi < 4; ++mi)                                            \
      _Pragma("unroll")                                                       \
      for (int ni = 0; ni < 4; ++ni)                                          \
        acc[mi][ni] = __builtin_amdgcn_mfma_f32_16x16x32_f16(                 \
            WREG[kk * 4 + ni], xf[mi], acc[mi][ni], 0, 0, 0);                 \
  }

#define LAYER(WPTR, LDW)                                                      \
  do {                                                                        \
    half8 wA[8], wB[8];                                                       \
    LOADW(wA, WPTR, LDW, 0);                                                  \
    _Pragma("unroll")                                                         \
    for (int k2 = 0; k2 < 4; ++k2) {                                          \
      LOADW(wB, WPTR, LDW, 2 * k2 + 1);                                       \
      COMPUTE(wA, 2 * k2);                                                    \
      if (2 * k2 + 2 < 8) LOADW(wA, WPTR, LDW, 2 * k2 + 2);                   \
      COMPUTE(wB, 2 * k2 + 1);                                                \
    }                                                                         \
  } while (0)

#define LSTAIL()                                                              \
  do {                                                                        \
    _Pragma("unroll")                                                         \
    for (int kk = 0; kk < 2; ++kk) {                                          \
      half8 xf[4], wf[4];                                                     \
      _Pragma("unroll")                                                       \
      for (int mi = 0; mi < 4; ++mi)                                          \
        xf[mi] = *(const half8*)(lsh +                                        \
            ((size_t)t * BATCH + rbg + mi * 16 + l15) * 64 + kk * 32 + l4 * 8);\
      _Pragma("unroll")                                                       \
      for (int ni = 0; ni < 4; ++ni)                                          \
        wf[ni] = *(const half8*)(W1h +                                        \
            (size_t)(nb + ni * 16 + l15) * 576 + 512 + kk * 32 + l4 * 8);     \
      _Pragma("unroll")                                                       \
      for (int mi = 0; mi < 4; ++mi)                                          \
        _Pragma("unroll")                                                     \
        for (int ni = 0; ni < 4; ++ni)                                        \
          acc[mi][ni] = __builtin_amdgcn_mfma_f32_16x16x32_f16(               \
              wf[ni], xf[mi], acc[mi][ni], 0, 0, 0);                          \
    }                                                                         \
  } while (0)

#define EPI(ACT, BIAS, GOUT)                                                  \
  do {                                                                        \
    __syncthreads();    /* all Xs reads of this layer done */                 \
    _Pragma("unroll")                                                         \
    for (int mi = 0; mi < 4; ++mi) {                                          \
      int r = mi * 16 + l15;                                                  \
      _Pragma("unroll")                                                       \
      for (int ni = 0; ni < 4; ++ni) {                                        \
        int c = nb + ni * 16 + l4 * 4;                                        \
        float4 bv = *(const float4*)&(BIAS)[c];                               \
        union { f16 h[4]; ushort4 u; } cv;                                    \
        float bb[4] = {bv.x, bv.y, bv.z, bv.w};                               \
        _Pragma("unroll")                                                     \
        for (int j4 = 0; j4 < 4; ++j4) {                                      \
          float v = acc[mi][ni][j4] + bb[j4];                                 \
          if (ACT == 1) v = fmaxf(v, 0.f);                                    \
          else { float xc = fminf(fmaxf(v, -9.f), 9.f);                       \
                 float e = __expf(2.f * xc); v = (e - 1.f) / (e + 1.f); }     \
          cv.h[j4] = (f16)v;                                                  \
        }                                                                     \
        int G = c >> 3;                                                       \
        *(ushort4*)(xb + (size_t)r * 1024 +                                   \
                    (((G ^ (r & 7)) << 4) | ((c * 2) & 15))) = cv.u;          \
        if (GOUT) *(ushort4*)((GOUT) +                                        \
                    ((size_t)t * BATCH + rbg + r) * HID + c) = cv.u;          \
      }                                                                       \
    }                                                                         \
    __syncthreads();                                                          \
  } while (0)

  // ---------------- layer 1: [h | ls_t] @ W1^T, relu ----------------
#pragma unroll
  for (int mi = 0; mi < 4; ++mi)
#pragma unroll
    for (int ni = 0; ni < 4; ++ni) acc[mi][ni] = (f32x4){0.f, 0.f, 0.f, 0.f};
  if (!FIRST) LAYER(W1h, 576);
  LSTAIL();
  EPI(1, b1, (ushort*)nullptr);
  // ---------------- layer 2: relu ----------------
#pragma unroll
  for (int mi = 0; mi < 4; ++mi)
#pragma unroll
    for (int ni = 0; ni < 4; ++ni) acc[mi][ni] = (f32x4){0.f, 0.f, 0.f, 0.f};
  LAYER(W2h, 512);
  EPI(1, b2, (ushort*)nullptr);
  // ---------------- layer 3: tanh -> Hall[t] ----------------
#pragma unroll
  for (int mi = 0; mi < 4; ++mi)
#pragma unroll
    for (int ni = 0; ni < 4; ++ni) acc[mi][ni] = (f32x4){0.f, 0.f, 0.f, 0.f};
  LAYER(W3h, 512);
  EPI(2, b3, Hall);
#undef LOADW
#undef COMPUTE
#undef LAYER
#undef LSTAIL
#undef EPI
}

// ---------------------------------------------------------------------------
// out[b, t, :] = Hall[t][b][:] @ Wout^T. 4 lanes per row, shfl reduce.
// ---------------------------------------------------------------------------
__global__ __launch_bounds__(256)
void out_k(const ushort* __restrict__ Hall, const float* __restrict__ Wout,
           float* __restrict__ out) {
  const int tid = threadIdx.x;
  const int lane4 = tid & 3;
  const int row = blockIdx.x * 64 + (tid >> 2);   // t*1024 + b
  const int t = row >> 10, b = row & 1023;
  const ushort* hb = Hall + (size_t)row * HID;
  float a0 = 0.f, a1 = 0.f, a2 = 0.f;
#pragma unroll 4
  for (int q = 0; q < 16; ++q) {
    int k = (q * 4 + lane4) * 8;
    half8 hv8 = *(const half8*)&hb[k];
#pragma unroll
    for (int j = 0; j < 8; ++j) {
      float h = (float)hv8[j];
      a0 += h * Wout[k + j];
      a1 += h * Wout[512 + k + j];
      a2 += h * Wout[1024 + k + j];
    }
  }
  a0 += __shfl_xor(a0, 1); a0 += __shfl_xor(a0, 2);
  a1 += __shfl_xor(a1, 1); a1 += __shfl_xor(a1, 2);
  a2 += __shfl_xor(a2, 1); a2 += __shfl_xor(a2, 2);
  if (lane4 == 0) {
    float* o = out + ((size_t)b * WIN + t) * 3;
    o[0] = a0; o[1] = a1; o[2] = a2;
  }
}

// ---------------------------------------------------------------------------
extern "C" void kernel_launch(void* const* d_in, const int* in_sizes, int n_in,
                              void* d_out, int out_size, void* d_ws, size_t ws_size,
                              hipStream_t stream) {
  (void)n_in; (void)out_size; (void)ws_size; (void)in_sizes;
  const float* z    = (const float*)d_in[0];
  const float* W1   = (const float*)d_in[1];
  const float* b1   = (const float*)d_in[2];
  const float* W2   = (const float*)d_in[3];
  const float* b2   = (const float*)d_in[4];
  const float* W3   = (const float*)d_in[5];
  const float* b3   = (const float*)d_in[6];
  const float* Wout = (const float*)d_in[7];
  float* out = (float*)d_out;

  // ---- replicate _static_schedule exactly (numpy linspace doubles) ----
  double tb[1000], tt[64], tu[20];
  {
    double sb = 1.0 / 999.0; for (int i = 0; i < 1000; ++i) tb[i] = i * sb; tb[999] = 1.0;
    double st = 1.0 / 63.0;  for (int k = 0; k < 64; ++k)  tt[k] = k * st;  tt[63] = 1.0;
    for (int j = 0; j < 20; ++j) tu[j] = tb[50 * j];
  }
  auto ssr = [](const double* a, int n, double v) -> int {
    int lo = 0, hi = n;
    while (lo < hi) { int mid = (lo + hi) >> 1; if (a[mid] <= v) lo = mid + 1; else hi = mid; }
    return lo - 1;
  };
  Sched sc; int gates[64];
  {
    int u_indices[20];
    for (int j = 0; j < 20; ++j) u_indices[j] = ssr(tb, 1000, tu[j]);
    double u_times[80]; int nut = 0; int last = -1;
    for (int k = 1; k < 64; ++k) {
      int it = ssr(tb, 1000, tt[k]);
      int iu = ssr(tu, 20, tt[k]); if (iu < 0) iu = 0;
      if (iu != last) { u_times[nut++] = tu[iu]; last = iu; }
      sc.starts[k - 1] = u_indices[iu];
      sc.ends[k - 1] = it;
    }
    u_times[nut++] = tt[63];
    int qh = 0;
    for (int k = 0; k < 64; ++k) {
      if (qh < nut && tt[k] >= u_times[qh]) { ++qh; gates[k] = 1; } else gates[k] = 0;
    }
  }
  int seg[64], g[64], ng = 0, jlast = -1;
  for (int t = 0; t < WIN; ++t) {
    seg[t] = jlast;
    if (gates[t]) { g[ng] = t; jlast = ng; ++ng; }
  }

  // ---- workspace carve ----
  char* p = (char*)d_ws;
  ushort* lsh  = (ushort*)p; p += (size_t)WIN * BATCH * 64 * 2;        // 8.4 MB
  ushort* W1h  = (ushort*)p; p += (size_t)HID * 576 * 2;
  ushort* W2h  = (ushort*)p; p += (size_t)HID * HID * 2;
  ushort* W3h  = (ushort*)p; p += (size_t)HID * HID * 2;
  ushort* Hall = (ushort*)p; p += (size_t)WIN * BATCH * HID * 2;       // 67 MB

  float scale = (float)std::sqrt(1.0 / 999.0);
  logsig_scan<<<BATCH, 256, 0, stream>>>(z, sc, lsh, scale);
  cvt_all<<<(HID * 72 + 2 * HID * 64 + 255) / 256, 256, 0, stream>>>(
      W1, W2, W3, W1h, W2h, W3h);

  // ---- serial per-segment rounds: ONE fused 3-layer launch each ----
  for (int r = 0; r < ng; ++r) {
    TL tlr; int cnt = 0;
    for (int t = 0; t < WIN && cnt < 8; ++t)
      if (seg[t] == r - 1) tlr.t[cnt++] = t;
    if (cnt == 0) continue;
    for (int i = cnt; i < 8; ++i) tlr.t[i] = tlr.t[0];
    if (r == 0) {
      round3<1><<<cnt * 16, 512, 0, stream>>>(nullptr, lsh, tlr,
                                              W1h, W2h, W3h, b1, b2, b3, Hall);
    } else {
      const ushort* carry = Hall + (size_t)g[r - 1] * (BATCH * HID);
      round3<0><<<cnt * 16, 512, 0, stream>>>(carry, lsh, tlr,
                                              W1h, W2h, W3h, b1, b2, b3, Hall);
    }
  }

  out_k<<<WIN * BATCH / 64, 256, 0, stream>>>(Hall, Wout, out);
}

// Round 13
// 662.618 us; speedup vs baseline: 1.8307x; 1.8307x over previous
//
#include <hip/hip_runtime.h>
#include <cmath>

#define WIN 64
#define HID 512
#define BATCH 1024
#define KIN 518

typedef _Float16 f16;
typedef _Float16 half8 __attribute__((ext_vector_type(8)));
typedef float f32x4 __attribute__((ext_vector_type(4)));
typedef unsigned short u16x4 __attribute__((ext_vector_type(4)));

struct Sched { int starts[63]; int ends[63]; };
struct TL { int t[8]; int gf[8]; };

// ---------------------------------------------------------------------------
// Parallel logsig scan (validated r3-r11) + in-kernel flag table.
// Writes lsh[t][b][64] fp16.
// ---------------------------------------------------------------------------
__global__ __launch_bounds__(256)
void logsig_scan(const float* __restrict__ z, Sched sc,
                 ushort* __restrict__ lsh, float scale) {
  __shared__ float zs[3000];
  __shared__ float Cs[20][3];
  __shared__ float wtot[4][6];
  __shared__ float earr[63][6];
  __shared__ short fe_s[1000];
  const int tid = threadIdx.x;
  const int b = blockIdx.x;
  const int ln = tid & 63, wv = tid >> 6;

  const float4* zrow = (const float4*)(z + (size_t)b * 3000);
  for (int i = tid; i < 750; i += 256) ((float4*)zs)[i] = zrow[i];
  for (int i = tid; i < 1000; i += 256) fe_s[i] = -1;
  if (tid == 0) { Cs[0][0] = 0.f; Cs[0][1] = 0.f; Cs[0][2] = 0.f; }
  __syncthreads();
  if (tid < 63) fe_s[sc.ends[tid]] = (short)tid;
  __syncthreads();

  const int p0 = 4 * tid + 1;
  int myfe[4];
#pragma unroll
  for (int i = 0; i < 4; ++i) myfe[i] = (p0 + i <= 999) ? fe_s[p0 + i] : -1;

  float d0 = 0.f, d1 = 0.f, d2 = 0.f, A0 = 0.f, A1 = 0.f, A2 = 0.f;
  if (p0 <= 999) {
    float b0 = 0.f, b1 = 0.f, b2 = 0.f;
#pragma unroll
    for (int i = 0; i < 4; ++i) {
      int p = p0 + i;
      if (p > 999) break;
      float n0 = b0 + zs[p * 3 + 0] * scale;
      float n1 = b1 + zs[p * 3 + 1] * scale;
      float n2 = b2 + zs[p * 3 + 2] * scale;
      A0 += 0.5f * (b0 * n1 - b1 * n0);
      A1 += 0.5f * (b0 * n2 - b2 * n0);
      A2 += 0.5f * (b1 * n2 - b2 * n1);
      b0 = n0; b1 = n1; b2 = n2;
    }
    d0 = b0; d1 = b1; d2 = b2;
  }

#pragma unroll
  for (int off = 1; off < 64; off <<= 1) {
    float e0 = __shfl(d0, ln - off), e1 = __shfl(d1, ln - off), e2 = __shfl(d2, ln - off);
    float eA0 = __shfl(A0, ln - off), eA1 = __shfl(A1, ln - off), eA2 = __shfl(A2, ln - off);
    if (ln >= off) {
      A0 = eA0 + A0 + 0.5f * (e0 * d1 - e1 * d0);
      A1 = eA1 + A1 + 0.5f * (e0 * d2 - e2 * d0);
      A2 = eA2 + A2 + 0.5f * (e1 * d2 - e2 * d1);
      d0 += e0; d1 += e1; d2 += e2;
    }
  }
  if (ln == 63) {
    wtot[wv][0] = d0; wtot[wv][1] = d1; wtot[wv][2] = d2;
    wtot[wv][3] = A0; wtot[wv][4] = A1; wtot[wv][5] = A2;
  }
  __syncthreads();

  float P0 = 0.f, P1 = 0.f, P2 = 0.f, PA0 = 0.f, PA1 = 0.f, PA2 = 0.f;
  for (int w = 0; w < wv; ++w) {
    float t0 = wtot[w][0], t1 = wtot[w][1], t2 = wtot[w][2];
    PA0 = PA0 + wtot[w][3] + 0.5f * (P0 * t1 - P1 * t0);
    PA1 = PA1 + wtot[w][4] + 0.5f * (P0 * t2 - P2 * t0);
    PA2 = PA2 + wtot[w][5] + 0.5f * (P1 * t2 - P2 * t1);
    P0 += t0; P1 += t1; P2 += t2;
  }
  float L0 = __shfl(d0, ln - 1), L1 = __shfl(d1, ln - 1), L2 = __shfl(d2, ln - 1);
  float LA0 = __shfl(A0, ln - 1), LA1 = __shfl(A1, ln - 1), LA2 = __shfl(A2, ln - 1);
  if (ln == 0) { L0 = L1 = L2 = LA0 = LA1 = LA2 = 0.f; }
  float bp0 = P0 + L0, bp1 = P1 + L1, bp2 = P2 + L2;
  float C0 = PA0 + LA0 + 0.5f * (P0 * L1 - P1 * L0);
  float C1 = PA1 + LA1 + 0.5f * (P0 * L2 - P2 * L0);
  float C2 = PA2 + LA2 + 0.5f * (P1 * L2 - P2 * L1);

  if (p0 <= 999) {
#pragma unroll
    for (int i = 0; i < 4; ++i) {
      int p = p0 + i;
      if (p > 999) break;
      float n0 = bp0 + zs[p * 3 + 0] * scale;
      float n1 = bp1 + zs[p * 3 + 1] * scale;
      float n2 = bp2 + zs[p * 3 + 2] * scale;
      C0 += 0.5f * (bp0 * n1 - bp1 * n0);
      C1 += 0.5f * (bp0 * n2 - bp2 * n0);
      C2 += 0.5f * (bp1 * n2 - bp2 * n1);
      bp0 = n0; bp1 = n1; bp2 = n2;
      if (p % 50 == 0) {
        int s = p / 50;
        Cs[s][0] = C0; Cs[s][1] = C1; Cs[s][2] = C2;
      }
      int k = myfe[i];
      if (k >= 0) {
        earr[k][0] = bp0; earr[k][1] = bp1; earr[k][2] = bp2;
        earr[k][3] = C0;  earr[k][4] = C1;  earr[k][5] = C2;
      }
    }
  }
  __syncthreads();

  if (tid < 63) {
    int s = sc.starts[tid] / 50;
    half8 v = {};
    v[0] = (f16)earr[tid][0]; v[1] = (f16)earr[tid][1]; v[2] = (f16)earr[tid][2];
    v[3] = (f16)(earr[tid][3] - Cs[s][0]);
    v[4] = (f16)(earr[tid][4] - Cs[s][1]);
    v[5] = (f16)(earr[tid][5] - Cs[s][2]);
    half8 zz = {};
    half8* d = (half8*)(lsh + ((size_t)(tid + 1) * BATCH + b) * 64);
    d[0] = v;
#pragma unroll
    for (int q = 1; q < 8; ++q) d[q] = zz;
  } else if (tid == 63) {
    half8 zz = {};
    half8* d = (half8*)(lsh + (size_t)b * 64);
#pragma unroll
    for (int q = 0; q < 8; ++q) d[q] = zz;
  }
}

// ---------------------------------------------------------------------------
// One-shot f32 -> f16 convert of all three weight matrices (K zero-padded).
// ---------------------------------------------------------------------------
__global__ __launch_bounds__(256)
void cvt_all(const float* __restrict__ W1, const float* __restrict__ W2,
             const float* __restrict__ W3, ushort* __restrict__ W1h,
             ushort* __restrict__ W2h, ushort* __restrict__ W3h) {
  const int n1 = HID * (576 / 8);
  const int n2 = HID * (HID / 8);
  int i = blockIdx.x * 256 + threadIdx.x;
  const float* src; ushort* dst; int Ks, Kd;
  if (i < n1)           { src = W1; dst = W1h; Ks = KIN; Kd = 576; }
  else if (i < n1 + n2) { src = W2; dst = W2h; Ks = HID; Kd = HID; i -= n1; }
  else if (i < n1 + 2 * n2) { src = W3; dst = W3h; Ks = HID; Kd = HID; i -= n1 + n2; }
  else return;
  int nblk = Kd >> 3;
  int row = i / nblk, k = (i - row * nblk) * 8;
  half8 v;
#pragma unroll
  for (int j = 0; j < 8; ++j) {
    int kk = k + j;
    float f = (kk < Ks) ? src[(size_t)row * Ks + kk] : 0.f;
    v[j] = (f16)f;
  }
  *(half8*)&dst[(size_t)row * Kd + k] = v;
}

// ---------------------------------------------------------------------------
// Per-round fp16 MFMA GEMM, counted-vmcnt double-buffer (r10-validated),
// XCD-LOCAL grid: blockIdx.x = row-slab (slab%8 -> XCD), blockIdx.y = 128-col
// strip. All 4 col-strips of a slab land on ONE XCD, so inter-layer act
// traffic and the round-to-round carry are L2-local, and W stays L2-resident.
// Non-gated SCAT outputs use nontemporal stores (read only by out_k).
// ---------------------------------------------------------------------------
template<int ACT, int L1, int SCAT>
__global__ __launch_bounds__(256)
void gemm_r(const ushort* __restrict__ A,
            const ushort* __restrict__ carry,
            const ushort* __restrict__ lsh,
            TL tl, int k0, int nk,
            const ushort* __restrict__ W, int ldw,
            const float* __restrict__ bias,
            ushort* __restrict__ C) {
  __shared__ ushort lds[32768];                   // 64KB: 2 x (X 16K | W 16K)
  char* ldsb = (char*)lds;
  const int tid = threadIdx.x;
  const int wv = tid >> 6, ln = tid & 63;
  const int slab = blockIdx.x;                    // row-slab: XCD = slab % 8
  const int bn0 = blockIdx.y * 128;               // col strip
  const int slot = slab >> 3;
  const int t = tl.t[slot];
  const int gated = tl.gf[slot];
  const size_t gr0 = (size_t)slab * 128;
  const ushort* lbase = lsh + (size_t)t * BATCH * 64;

  f32x4 acc[4][4];
#pragma unroll
  for (int mi = 0; mi < 4; ++mi)
#pragma unroll
    for (int ni = 0; ni < 4; ++ni) acc[mi][ni] = (f32x4){0.f, 0.f, 0.f, 0.f};

  const int xr0 = (wv >> 1) * 64, nr0 = (wv & 1) * 64;
  const int l15 = ln & 15, l4 = ln >> 4;

#define STAGE(BI, KT)                                                         \
  do {                                                                        \
    _Pragma("unroll")                                                         \
    for (int i = 0; i < 4; ++i) {                                             \
      int qq = (i * 4 + wv) * 64 + ln;                                        \
      int r = qq >> 3, sl = qq & 7, ss = sl ^ (r & 7);                        \
      const ushort* src;                                                      \
      if (L1) {                                                               \
        int b_ = ((slab & 7) << 7) + r;                                       \
        if ((KT) < 8) src = carry + (size_t)b_ * HID + (KT) * 64 + ss * 8;    \
        else          src = lbase + (size_t)b_ * 64 + ss * 8;                 \
      } else {                                                                \
        src = A + (gr0 + r) * (size_t)HID + (KT) * 64 + ss * 8;               \
      }                                                                       \
      __builtin_amdgcn_global_load_lds(                                       \
          (const __attribute__((address_space(1))) unsigned int*)src,         \
          (__attribute__((address_space(3))) unsigned int*)                   \
              (ldsb + (BI) * 32768 + (i * 4 + wv) * 1024), 16, 0, 0);         \
    }                                                                         \
    _Pragma("unroll")                                                         \
    for (int i = 0; i < 4; ++i) {                                             \
      int qq = (i * 4 + wv) * 64 + ln;                                        \
      int r = qq >> 3, sl = qq & 7, ss = sl ^ (r & 7);                        \
      const ushort* src = W + (size_t)(bn0 + r) * ldw + (KT) * 64 + ss * 8;   \
      __builtin_amdgcn_global_load_lds(                                       \
          (const __attribute__((address_space(1))) unsigned int*)src,         \
          (__attribute__((address_space(3))) unsigned int*)                   \
              (ldsb + (BI) * 32768 + 16384 + (i * 4 + wv) * 1024), 16, 0, 0); \
    }                                                                         \
  } while (0)

  STAGE(0, k0);
  int cur = 0;
  for (int kt = k0; kt < nk; ++kt) {
    const bool pf = (kt + 1 < nk);
    if (pf) {
      STAGE(cur ^ 1, kt + 1);                    // 8 more loads in flight
      asm volatile("s_waitcnt vmcnt(8)" ::: "memory");   // cur's 8 retired
    } else {
      asm volatile("s_waitcnt vmcnt(0)" ::: "memory");
    }
    __builtin_amdgcn_s_barrier();
    __builtin_amdgcn_sched_barrier(0);
#pragma unroll
    for (int kk = 0; kk < 2; ++kk) {
      half8 xf[4], wf[4];
#pragma unroll
      for (int mi = 0; mi < 4; ++mi) {
        int r = xr0 + mi * 16 + l15;
        int ss = (kk * 4 + l4) ^ (r & 7);
        xf[mi] = *(const half8*)(ldsb + cur * 32768 + r * 128 + ss * 16);
      }
#pragma unroll
      for (int ni = 0; ni < 4; ++ni) {
        int r = nr0 + ni * 16 + l15;
        int ss = (kk * 4 + l4) ^ (r & 7);
        wf[ni] = *(const half8*)(ldsb + cur * 32768 + 16384 + r * 128 + ss * 16);
      }
#pragma unroll
      for (int mi = 0; mi < 4; ++mi)
#pragma unroll
        for (int ni = 0; ni < 4; ++ni)
          acc[mi][ni] = __builtin_amdgcn_mfma_f32_16x16x32_f16(wf[ni], xf[mi], acc[mi][ni], 0, 0, 0);
    }
    __builtin_amdgcn_sched_barrier(0);
    asm volatile("s_waitcnt lgkmcnt(0)" ::: "memory");
    __builtin_amdgcn_s_barrier();
    cur ^= 1;
  }
#undef STAGE

  // ---- epilogue: bias + act + f16 pack, 8B stores ----
#pragma unroll
  for (int mi = 0; mi < 4; ++mi) {
    size_t gm;
    if (SCAT) gm = (size_t)t * BATCH + ((slab & 7) << 7) + xr0 + mi * 16 + l15;
    else      gm = gr0 + xr0 + mi * 16 + l15;
#pragma unroll
    for (int ni = 0; ni < 4; ++ni) {
      int gn = bn0 + nr0 + ni * 16 + l4 * 4;
      f32x4 a = acc[mi][ni];
      union { f16 h[4]; u16x4 u; } cv;
#pragma unroll
      for (int j = 0; j < 4; ++j) {
        float v = a[j] + bias[gn + j];
        if (ACT == 1) v = fmaxf(v, 0.f);
        else { float xc = fminf(fmaxf(v, -9.f), 9.f); float e = __expf(2.f * xc); v = (e - 1.f) / (e + 1.f); }
        cv.h[j] = (f16)v;
      }
      u16x4* dst = (u16x4*)&C[gm * HID + gn];
      if (SCAT && !gated) __builtin_nontemporal_store(cv.u, dst);
      else                *dst = cv.u;
    }
  }
}

// ---------------------------------------------------------------------------
// out[b, t, :] = Hall[t][b][:] @ Wout^T. 4 lanes per row, shfl reduce.
// ---------------------------------------------------------------------------
__global__ __launch_bounds__(256)
void out_k(const ushort* __restrict__ Hall, const float* __restrict__ Wout,
           float* __restrict__ out) {
  const int tid = threadIdx.x;
  const int lane4 = tid & 3;
  const int row = blockIdx.x * 64 + (tid >> 2);   // t*1024 + b
  const int t = row >> 10, b = row & 1023;
  const ushort* hb = Hall + (size_t)row * HID;
  float a0 = 0.f, a1 = 0.f, a2 = 0.f;
#pragma unroll 4
  for (int q = 0; q < 16; ++q) {
    int k = (q * 4 + lane4) * 8;
    half8 hv8 = *(const half8*)&hb[k];
#pragma unroll
    for (int j = 0; j < 8; ++j) {
      float h = (float)hv8[j];
      a0 += h * Wout[k + j];
      a1 += h * Wout[512 + k + j];
      a2 += h * Wout[1024 + k + j];
    }
  }
  a0 += __shfl_xor(a0, 1); a0 += __shfl_xor(a0, 2);
  a1 += __shfl_xor(a1, 1); a1 += __shfl_xor(a1, 2);
  a2 += __shfl_xor(a2, 1); a2 += __shfl_xor(a2, 2);
  if (lane4 == 0) {
    float* o = out + ((size_t)b * WIN + t) * 3;
    o[0] = a0; o[1] = a1; o[2] = a2;
  }
}

// ---------------------------------------------------------------------------
extern "C" void kernel_launch(void* const* d_in, const int* in_sizes, int n_in,
                              void* d_out, int out_size, void* d_ws, size_t ws_size,
                              hipStream_t stream) {
  (void)n_in; (void)out_size; (void)ws_size; (void)in_sizes;
  const float* z    = (const float*)d_in[0];
  const float* W1   = (const float*)d_in[1];
  const float* b1   = (const float*)d_in[2];
  const float* W2   = (const float*)d_in[3];
  const float* b2   = (const float*)d_in[4];
  const float* W3   = (const float*)d_in[5];
  const float* b3   = (const float*)d_in[6];
  const float* Wout = (const float*)d_in[7];
  float* out = (float*)d_out;

  // ---- replicate _static_schedule exactly (numpy linspace doubles) ----
  double tb[1000], tt[64], tu[20];
  {
    double sb = 1.0 / 999.0; for (int i = 0; i < 1000; ++i) tb[i] = i * sb; tb[999] = 1.0;
    double st = 1.0 / 63.0;  for (int k = 0; k < 64; ++k)  tt[k] = k * st;  tt[63] = 1.0;
    for (int j = 0; j < 20; ++j) tu[j] = tb[50 * j];
  }
  auto ssr = [](const double* a, int n, double v) -> int {
    int lo = 0, hi = n;
    while (lo < hi) { int mid = (lo + hi) >> 1; if (a[mid] <= v) lo = mid + 1; else hi = mid; }
    return lo - 1;
  };
  Sched sc; int gates[64];
  {
    int u_indices[20];
    for (int j = 0; j < 20; ++j) u_indices[j] = ssr(tb, 1000, tu[j]);
    double u_times[80]; int nut = 0; int last = -1;
    for (int k = 1; k < 64; ++k) {
      int it = ssr(tb, 1000, tt[k]);
      int iu = ssr(tu, 20, tt[k]); if (iu < 0) iu = 0;
      if (iu != last) { u_times[nut++] = tu[iu]; last = iu; }
      sc.starts[k - 1] = u_indices[iu];
      sc.ends[k - 1] = it;
    }
    u_times[nut++] = tt[63];
    int qh = 0;
    for (int k = 0; k < 64; ++k) {
      if (qh < nut && tt[k] >= u_times[qh]) { ++qh; gates[k] = 1; } else gates[k] = 0;
    }
  }
  int seg[64], g[64], ng = 0, jlast = -1;
  for (int t = 0; t < WIN; ++t) {
    seg[t] = jlast;
    if (gates[t]) { g[ng] = t; jlast = ng; ++ng; }
  }

  // ---- workspace carve ----
  char* p = (char*)d_ws;
  ushort* lsh  = (ushort*)p; p += (size_t)WIN * BATCH * 64 * 2;        // 8.4 MB
  ushort* W1h  = (ushort*)p; p += (size_t)HID * 576 * 2;
  ushort* W2h  = (ushort*)p; p += (size_t)HID * HID * 2;
  ushort* W3h  = (ushort*)p; p += (size_t)HID * HID * 2;
  ushort* Hall = (ushort*)p; p += (size_t)WIN * BATCH * HID * 2;       // 67 MB
  ushort* act1 = (ushort*)p; p += (size_t)8 * BATCH * HID * 2;         // 8.4 MB
  ushort* act2 = (ushort*)p; p += (size_t)8 * BATCH * HID * 2;         // 8.4 MB

  float scale = (float)std::sqrt(1.0 / 999.0);
  logsig_scan<<<BATCH, 256, 0, stream>>>(z, sc, lsh, scale);
  cvt_all<<<(HID * 72 + 2 * HID * 64 + 255) / 256, 256, 0, stream>>>(
      W1, W2, W3, W1h, W2h, W3h);

  // ---- serial per-segment rounds: 3 XCD-local GEMM launches each ----
  for (int r = 0; r < ng; ++r) {
    TL tlr; int cnt = 0;
    for (int t = 0; t < WIN && cnt < 8; ++t)
      if (seg[t] == r - 1) tlr.t[cnt++] = t;
    if (cnt == 0) continue;
    for (int i = cnt; i < 8; ++i) tlr.t[i] = tlr.t[0];
    for (int i = 0; i < 8; ++i) tlr.gf[i] = (tlr.t[i] == g[r]) ? 1 : 0;
    const ushort* carry = (r == 0) ? nullptr : Hall + (size_t)g[r - 1] * (BATCH * HID);
    int k0 = (r == 0) ? 8 : 0;                    // round 0: zero carry, ls only
    dim3 gg(cnt * 8, 4), gb(256);                 // x = row-slab -> XCD-local
    gemm_r<1, 1, 0><<<gg, gb, 0, stream>>>(nullptr, carry, lsh, tlr, k0, 9,
                                           W1h, 576, b1, act1);
    gemm_r<1, 0, 0><<<gg, gb, 0, stream>>>(act1, nullptr, lsh, tlr, 0, 8,
                                           W2h, HID, b2, act2);
    gemm_r<2, 0, 1><<<gg, gb, 0, stream>>>(act2, nullptr, lsh, tlr, 0, 8,
                                           W3h, HID, b3, Hall);
  }

  out_k<<<WIN * BATCH / 64, 256, 0, stream>>>(Hall, Wout, out);
}